// Round 24
// baseline (79.746 us; speedup 1.0000x reference)
//
#include <hip/hip_runtime.h>

typedef __attribute__((ext_vector_type(8))) short bf16x8;   // 8 bf16 = 4 VGPRs
typedef __attribute__((ext_vector_type(4))) float f32x4;    // MFMA acc

#define NBKT 4096         // padded bucket array (real buckets = ceil(N/16) = 3125)
#define BDST 16           // dsts per bucket
#define BCAP 512          // fixed bucket capacity (mean 256, sigma ~16 -> 16-sigma)

// fp32 -> bf16 round-to-nearest-even
__device__ __forceinline__ unsigned short f2bf(float f) {
  unsigned int u = __float_as_uint(f);
  return (unsigned short)((u + 0x7FFFu + ((u >> 16) & 1u)) >> 16);
}

// ---------------- MFMA bf16 GEMM (GEMM2): out = act(A @ W + bias) ----------------
// 512 threads = 8 waves sharing ONE swizzled BTl staging (byte ^= (row&7)<<4);
// block covers 128 rows. Fragment layout (m89/m91-verified).
template<int K, bool RELU, bool OBF16, bool A_F32>
__global__ __launch_bounds__(512) void gemm_mfma(const void* __restrict__ Av,
                                                 const unsigned short* __restrict__ BT,
                                                 const float* __restrict__ bias,
                                                 void* __restrict__ outv, int M) {
  __shared__ unsigned short BTl[128 * K];
  const int t = threadIdx.x;
  const int w = t >> 6;               // wave 0..7
  const int l = t & 63;
  const int r0 = blockIdx.x * 128 + w * 16;
  const int arow = l & 15;
  const int kq = l >> 4;

  constexpr int CPR = K / 8;
  constexpr int TOTAL = 128 * CPR;
  constexpr int CPT = TOTAL / 512;
  static_assert(CPT * 512 == TOTAL, "staging must cover all of BTl");
#pragma unroll
  for (int c = 0; c < CPT; ++c) {
    int idx = c * 512 + t;
    int row = idx / CPR;
    int within = idx % CPR;
    unsigned swz = (unsigned)(within * 16) ^ ((unsigned)(row & 7) << 4);
    *(uint4*)((char*)BTl + (size_t)row * (K * 2) + swz) =
        *(const uint4*)(BT + (size_t)row * K + within * 8);
  }
  __syncthreads();

  int rowA = r0 + arow; if (rowA >= M) rowA = M - 1;

  f32x4 acc[8];
#pragma unroll
  for (int n = 0; n < 8; ++n) acc[n] = (f32x4){0.f, 0.f, 0.f, 0.f};

#pragma unroll
  for (int ks = 0; ks < K / 32; ++ks) {
    bf16x8 a;
    if (A_F32) {
      const float* ap = (const float*)Av + (size_t)rowA * K + ks * 32 + kq * 8;
      float4 f0 = *(const float4*)ap;
      float4 f1 = *(const float4*)(ap + 4);
      a[0] = (short)f2bf(f0.x); a[1] = (short)f2bf(f0.y);
      a[2] = (short)f2bf(f0.z); a[3] = (short)f2bf(f0.w);
      a[4] = (short)f2bf(f1.x); a[5] = (short)f2bf(f1.y);
      a[6] = (short)f2bf(f1.z); a[7] = (short)f2bf(f1.w);
    } else {
      a = *(const bf16x8*)((const unsigned short*)Av + (size_t)rowA * K + ks * 32 + kq * 8);
    }
#pragma unroll
    for (int n = 0; n < 8; ++n) {
      int rowB = n * 16 + arow;
      unsigned boff = (unsigned)(ks * 64 + kq * 16) ^ ((unsigned)(rowB & 7) << 4);
      bf16x8 b = *(const bf16x8*)((const char*)BTl + (size_t)rowB * (K * 2) + boff);
      acc[n] = __builtin_amdgcn_mfma_f32_16x16x32_bf16(a, b, acc[n], 0, 0, 0);
    }
  }

#pragma unroll
  for (int n = 0; n < 8; ++n) {
    int col = n * 16 + arow;
    float bv = bias[col];
#pragma unroll
    for (int j = 0; j < 4; ++j) {
      int row = r0 + kq * 4 + j;
      if (row < M) {
        float v = acc[n][j] + bv;
        if (RELU) v = fmaxf(v, 0.f);
        if (OBF16) ((unsigned short*)outv)[(size_t)row * 128 + col] = f2bf(v);
        else       ((float*)outv)[(size_t)row * 128 + col] = v;
      }
    }
  }
}

// ---- W^T bf16 prep (blocks 0..191) + bcnt zero (block 192, all NBKT entries) ----
__global__ __launch_bounds__(256) void prep_wt(const float* __restrict__ Wp,
                                               const float* __restrict__ Wa,
                                               unsigned short* __restrict__ WpT,
                                               unsigned short* __restrict__ WaT,
                                               int* __restrict__ bcnt) {
  const int b = blockIdx.x;
  if (b == 192) {
    for (int i = threadIdx.x; i < NBKT; i += 256) bcnt[i] = 0;   // covers ALL of bcnt
    return;
  }
  int i = b * 256 + threadIdx.x;
  if (i < 128 * 256) {                 // WpT[128][256] <- Wp[256][128]
    int c = i >> 8, k = i & 255;
    WpT[i] = f2bf(Wp[k * 128 + c]);
  } else if (i < 128 * 256 + 128 * 128) {
    int j = i - 128 * 256;             // WaT[128][128] <- Wa[128][128]
    int c = j >> 7, k = j & 127;
    WaT[j] = f2bf(Wa[k * 128 + c]);
  }
}

// ---- fused independent stages: bin_fill (blocks 0..nchunks-1) + GEMM1 (rest) ----
// 512 threads, 32KB LDS (4 blocks/CU). GEMM1 stages WpT in TWO 32KB K-halves.
// Fill writes fixed-capacity buckets: binned[b*BCAP + rank], rank via bcnt atomics.
// Fill's cnt[4096]+base[4096] = 32KB aliases BTl EXACTLY (static_assert below).
__global__ __launch_bounds__(512) void g1_fill(
    const float* __restrict__ features, const unsigned short* __restrict__ WpT,
    const float* __restrict__ bp, unsigned short* __restrict__ xb, int M,
    const int* __restrict__ ei, const float* __restrict__ ew,
    int* __restrict__ bcnt, uint2* __restrict__ binned, int E, int nchunks) {
  __shared__ unsigned short BTl[128 * 128];   // 32KB
  static_assert(2 * NBKT * sizeof(int) <= sizeof(unsigned short) * 128 * 128,
                "fill's cnt+base must fit in BTl alias");
  const int t = threadIdx.x;

  if ((int)blockIdx.x < nchunks) {
    // ---------- bin_fill branch (4096 edges, 8 per thread) ----------
    int* cnt  = (int*)BTl;          // 16KB (NBKT=4096)
    int* base = cnt + NBKT;         // 16KB
    const int c0 = blockIdx.x * 4096;
    for (int i = t; i < NBKT; i += 512) cnt[i] = 0;
    __syncthreads();

    int dst[8]; unsigned pk[8]; int rnk[8];
#pragma unroll
    for (int i = 0; i < 8; ++i) {
      int e = c0 + i * 512 + t;
      if (e < E) {
        int d = ei[E + e];
        dst[i] = d;
        pk[i] = ((unsigned)ei[e] << 16) | (unsigned)f2bf(ew[e]);
        rnk[i] = atomicAdd(&cnt[d >> 4], 1);
      } else dst[i] = -1;
    }
    __syncthreads();
    for (int i = t; i < NBKT; i += 512) {
      int c = cnt[i];
      base[i] = c ? atomicAdd(&bcnt[i], c) : 0;
    }
    __syncthreads();
#pragma unroll
    for (int i = 0; i < 8; ++i) {
      if (dst[i] >= 0) {
        int b = dst[i] >> 4;
        binned[(size_t)b * BCAP + base[b] + rnk[i]] =
            make_uint2((unsigned)(dst[i] & 15), pk[i]);
      }
    }
    return;
  }

  // ---------- GEMM1 branch: xb = bf16(features @ WpT^T + bp), K=256 ----------
  const int bid = blockIdx.x - nchunks;
  const int w = t >> 6;               // wave 0..7
  const int l = t & 63;
  const int r0 = bid * 128 + w * 16;
  const int arow = l & 15;
  const int kq = l >> 4;

  int rowA = r0 + arow; if (rowA >= M) rowA = M - 1;

  f32x4 acc[8];
#pragma unroll
  for (int n = 0; n < 8; ++n) acc[n] = (f32x4){0.f, 0.f, 0.f, 0.f};

#pragma unroll
  for (int h = 0; h < 2; ++h) {       // two 32KB K-halves of WpT
    if (h) __syncthreads();           // all waves done with previous half
#pragma unroll
    for (int c = 0; c < 4; ++c) {     // stage: 2048 chunks of 16B, 4/thread
      int idx = c * 512 + t;
      int row = idx >> 4;             // 0..127
      int within = idx & 15;          // 0..15 (16 chunks per 256B row)
      unsigned swz = (unsigned)(within * 16) ^ ((unsigned)(row & 7) << 4);
      *(uint4*)((char*)BTl + (size_t)row * 256 + swz) =
          *(const uint4*)(WpT + (size_t)row * 256 + h * 128 + within * 8);
    }
    __syncthreads();
#pragma unroll
    for (int ks4 = 0; ks4 < 4; ++ks4) {
      int ks = h * 4 + ks4;
      const float* ap = features + (size_t)rowA * 256 + ks * 32 + kq * 8;
      float4 f0 = *(const float4*)ap;
      float4 f1 = *(const float4*)(ap + 4);
      bf16x8 a;
      a[0] = (short)f2bf(f0.x); a[1] = (short)f2bf(f0.y);
      a[2] = (short)f2bf(f0.z); a[3] = (short)f2bf(f0.w);
      a[4] = (short)f2bf(f1.x); a[5] = (short)f2bf(f1.y);
      a[6] = (short)f2bf(f1.z); a[7] = (short)f2bf(f1.w);
#pragma unroll
      for (int n = 0; n < 8; ++n) {
        int rowB = n * 16 + arow;
        unsigned boff = (unsigned)(ks4 * 64 + kq * 16) ^ ((unsigned)(rowB & 7) << 4);
        bf16x8 b = *(const bf16x8*)((const char*)BTl + (size_t)rowB * 256 + boff);
        acc[n] = __builtin_amdgcn_mfma_f32_16x16x32_bf16(a, b, acc[n], 0, 0, 0);
      }
    }
  }

#pragma unroll
  for (int n = 0; n < 8; ++n) {
    int col = n * 16 + arow;
    float bv = bp[col];
#pragma unroll
    for (int j = 0; j < 4; ++j) {
      int row = r0 + kq * 4 + j;
      if (row < M) {
        float v = acc[n][j] + bv;
        xb[(size_t)row * 128 + col] = f2bf(v);
      }
    }
  }
}

// ---------------- counting-sort + register-accumulate gather ----------------
// One block (512 thr) per 16-dst bucket (3126 blocks -> ~12 blocks/CU grid,
// 4 resident). Bucket b at binned[b*BCAP .. b*BCAP+bcnt[b]); single sort pass.
__global__ __launch_bounds__(512) void bucket_sort_gather(
    const unsigned short* __restrict__ xb,
    const uint2* __restrict__ binned,
    const int* __restrict__ bcnt,
    unsigned short* __restrict__ aggb, int N) {
  __shared__ unsigned sorted[BCAP];    // 2 KB
  __shared__ int cnt[BDST];
  __shared__ int scn[BDST];
  __shared__ int start[BDST];

  const int b = blockIdx.x;
  const int t = threadIdx.x;
  const int w = t >> 6, l = t & 63;
  const int cc0 = l * 2;
  const int n = min(bcnt[b], BCAP);
  const int js = b * BCAP;

  float2 acc[2];
#pragma unroll
  for (int i = 0; i < 2; ++i) acc[i] = make_float2(0.f, 0.f);

  if (t < BDST) cnt[t] = 0;
  __syncthreads();

  int dl = -1; unsigned pk; int rk;
  if (t < n) {
    uint2 e = binned[js + t];
    dl = (int)e.x; pk = e.y;
    rk = atomicAdd(&cnt[dl], 1);       // native int LDS atomic
  }
  __syncthreads();

  if (t < BDST) scn[t] = cnt[t];
  __syncthreads();
#pragma unroll
  for (int o = 1; o < BDST; o <<= 1) {
    int v = 0;
    if (t < BDST && t >= o) v = scn[t - o];
    __syncthreads();
    if (t < BDST) scn[t] += v;
    __syncthreads();
  }
  if (t < BDST) start[t] = scn[t] - cnt[t];
  __syncthreads();

  if (dl >= 0) sorted[start[dl] + rk] = pk;
  __syncthreads();

  // accumulate: wave w owns dl in {w*2, w*2+1}; 8 gathers in flight
  for (int i = 0; i < 2; ++i) {
    const int d = w * 2 + i;
    const int s0 = start[d], c = cnt[d];   // wave-uniform LDS broadcast
    int j = 0;
    for (; j + 8 <= c; j += 8) {
      unsigned p[8], v[8];
#pragma unroll
      for (int q = 0; q < 8; ++q) p[q] = sorted[s0 + j + q];
#pragma unroll
      for (int q = 0; q < 8; ++q)
        v[q] = *(const unsigned*)(xb + (size_t)(p[q] >> 16) * 128 + cc0);
#pragma unroll
      for (int q = 0; q < 8; ++q) {
        float wg = __uint_as_float(p[q] << 16);
        acc[i].x = fmaf(wg, __uint_as_float(v[q] << 16), acc[i].x);
        acc[i].y = fmaf(wg, __uint_as_float(v[q] & 0xFFFF0000u), acc[i].y);
      }
    }
    for (; j + 4 <= c; j += 4) {
      unsigned p[4], v[4];
#pragma unroll
      for (int q = 0; q < 4; ++q) p[q] = sorted[s0 + j + q];
#pragma unroll
      for (int q = 0; q < 4; ++q)
        v[q] = *(const unsigned*)(xb + (size_t)(p[q] >> 16) * 128 + cc0);
#pragma unroll
      for (int q = 0; q < 4; ++q) {
        float wg = __uint_as_float(p[q] << 16);
        acc[i].x = fmaf(wg, __uint_as_float(v[q] << 16), acc[i].x);
        acc[i].y = fmaf(wg, __uint_as_float(v[q] & 0xFFFF0000u), acc[i].y);
      }
    }
    for (; j < c; ++j) {
      unsigned p = sorted[s0 + j];
      unsigned v = *(const unsigned*)(xb + (size_t)(p >> 16) * 128 + cc0);
      float wg = __uint_as_float(p << 16);
      acc[i].x = fmaf(wg, __uint_as_float(v << 16), acc[i].x);
      acc[i].y = fmaf(wg, __uint_as_float(v & 0xFFFF0000u), acc[i].y);
    }
  }

  // writeback: wave w writes its 2 dst rows (coalesced 256B per row)
  const int d0 = b * BDST;
#pragma unroll
  for (int i = 0; i < 2; ++i) {
    int dst = d0 + w * 2 + i;
    if (dst < N) {
      unsigned p = ((unsigned)f2bf(acc[i].y) << 16) | (unsigned)f2bf(acc[i].x);
      *(unsigned*)(aggb + (size_t)dst * 128 + cc0) = p;
    }
  }
}

extern "C" void kernel_launch(void* const* d_in, const int* in_sizes, int n_in,
                              void* d_out, int out_size, void* d_ws, size_t ws_size,
                              hipStream_t stream) {
  const float* features = (const float*)d_in[0];
  const int* ei = (const int*)d_in[1];   // [2, E] int32
  const float* ew = (const float*)d_in[2];
  const float* Wp = (const float*)d_in[3];
  const float* bp = (const float*)d_in[4];
  const float* Wa = (const float*)d_in[5];
  const float* ba = (const float*)d_in[6];

  const int N = in_sizes[0] / 256;  // 50000
  const int E = in_sizes[1] / 2;    // 800000

  float* out = (float*)d_out;

  // Workspace layout (256B-aligned), ~42.5 MB:
  char* ws = (char*)d_ws;
  size_t o = 0;
  unsigned short* xb   = (unsigned short*)(ws + o); o += (size_t)N * 128 * 2;  // 12.8 MB
  o = (o + 255) & ~(size_t)255;
  unsigned short* aggb = (unsigned short*)(ws + o); o += (size_t)N * 128 * 2;  // 12.8 MB
  o = (o + 255) & ~(size_t)255;
  uint2* binned = (uint2*)(ws + o); o += (size_t)NBKT * BCAP * 8;              // 16.8 MB
  o = (o + 255) & ~(size_t)255;
  int* bcnt  = (int*)(ws + o); o += NBKT * 4;
  o = (o + 255) & ~(size_t)255;
  unsigned short* WpT = (unsigned short*)(ws + o); o += (size_t)128 * 256 * 2; // 64 KB
  o = (o + 255) & ~(size_t)255;
  unsigned short* WaT = (unsigned short*)(ws + o); o += (size_t)128 * 128 * 2; // 32 KB

  const int nbkt_real = (N + BDST - 1) / BDST;  // 3125
  const int nchunks = (E + 4095) / 4096;        // 196
  const int g1_blocks = (N + 127) / 128;        // 391

  // 0) W^T prep (blocks 0..191) + bcnt zero (block 192)
  prep_wt<<<193, 256, 0, stream>>>(Wp, Wa, WpT, WaT, bcnt);

  // 1) fused independent stages: bin_fill (blocks 0..195) + GEMM1 (blocks 196..586)
  g1_fill<<<nchunks + g1_blocks, 512, 0, stream>>>(features, WpT, bp, xb, N,
                                                   ei, ew, bcnt, binned, E, nchunks);

  // 2) per-bucket counting-sort + register-accumulated gather (no float atomics)
  bucket_sort_gather<<<nbkt_real, 512, 0, stream>>>(xb, binned, bcnt, aggb, N);

  // 3) out = relu(aggb @ W_agg + b_agg)  (512-thr, 128 rows/block)
  gemm_mfma<128, true, false, false><<<(N + 127) / 128, 512, 0, stream>>>(aggb, WaT, ba, out, N);
}

// Round 25
// 76.289 us; speedup vs baseline: 1.0453x; 1.0453x over previous
//
#include <hip/hip_runtime.h>

typedef __attribute__((ext_vector_type(8))) short bf16x8;   // 8 bf16 = 4 VGPRs
typedef __attribute__((ext_vector_type(4))) float f32x4;    // MFMA acc

#define NBKT 2048         // padded bucket array (real buckets = ceil(N/32) = 1563)
#define BDST 32           // dsts per bucket
#define BCAP 1024         // fixed bucket capacity (mean 512, sigma ~23 -> 22-sigma)
#define CHUNK 1024        // entries per sort pass (== BCAP: single pass)

// fp32 -> bf16 round-to-nearest-even
__device__ __forceinline__ unsigned short f2bf(float f) {
  unsigned int u = __float_as_uint(f);
  return (unsigned short)((u + 0x7FFFu + ((u >> 16) & 1u)) >> 16);
}

// ---------------- MFMA bf16 GEMM (GEMM2): out = act(A @ W + bias) ----------------
// 512 threads = 8 waves sharing ONE swizzled BTl staging (byte ^= (row&7)<<4);
// block covers 128 rows. Fragment layout (m89/m91-verified).
template<int K, bool RELU, bool OBF16, bool A_F32>
__global__ __launch_bounds__(512) void gemm_mfma(const void* __restrict__ Av,
                                                 const unsigned short* __restrict__ BT,
                                                 const float* __restrict__ bias,
                                                 void* __restrict__ outv, int M) {
  __shared__ unsigned short BTl[128 * K];
  const int t = threadIdx.x;
  const int w = t >> 6;               // wave 0..7
  const int l = t & 63;
  const int r0 = blockIdx.x * 128 + w * 16;
  const int arow = l & 15;
  const int kq = l >> 4;

  constexpr int CPR = K / 8;
  constexpr int TOTAL = 128 * CPR;
  constexpr int CPT = TOTAL / 512;
  static_assert(CPT * 512 == TOTAL, "staging must cover all of BTl");
#pragma unroll
  for (int c = 0; c < CPT; ++c) {
    int idx = c * 512 + t;
    int row = idx / CPR;
    int within = idx % CPR;
    unsigned swz = (unsigned)(within * 16) ^ ((unsigned)(row & 7) << 4);
    *(uint4*)((char*)BTl + (size_t)row * (K * 2) + swz) =
        *(const uint4*)(BT + (size_t)row * K + within * 8);
  }
  __syncthreads();

  int rowA = r0 + arow; if (rowA >= M) rowA = M - 1;

  f32x4 acc[8];
#pragma unroll
  for (int n = 0; n < 8; ++n) acc[n] = (f32x4){0.f, 0.f, 0.f, 0.f};

#pragma unroll
  for (int ks = 0; ks < K / 32; ++ks) {
    bf16x8 a;
    if (A_F32) {
      const float* ap = (const float*)Av + (size_t)rowA * K + ks * 32 + kq * 8;
      float4 f0 = *(const float4*)ap;
      float4 f1 = *(const float4*)(ap + 4);
      a[0] = (short)f2bf(f0.x); a[1] = (short)f2bf(f0.y);
      a[2] = (short)f2bf(f0.z); a[3] = (short)f2bf(f0.w);
      a[4] = (short)f2bf(f1.x); a[5] = (short)f2bf(f1.y);
      a[6] = (short)f2bf(f1.z); a[7] = (short)f2bf(f1.w);
    } else {
      a = *(const bf16x8*)((const unsigned short*)Av + (size_t)rowA * K + ks * 32 + kq * 8);
    }
#pragma unroll
    for (int n = 0; n < 8; ++n) {
      int rowB = n * 16 + arow;
      unsigned boff = (unsigned)(ks * 64 + kq * 16) ^ ((unsigned)(rowB & 7) << 4);
      bf16x8 b = *(const bf16x8*)((const char*)BTl + (size_t)rowB * (K * 2) + boff);
      acc[n] = __builtin_amdgcn_mfma_f32_16x16x32_bf16(a, b, acc[n], 0, 0, 0);
    }
  }

#pragma unroll
  for (int n = 0; n < 8; ++n) {
    int col = n * 16 + arow;
    float bv = bias[col];
#pragma unroll
    for (int j = 0; j < 4; ++j) {
      int row = r0 + kq * 4 + j;
      if (row < M) {
        float v = acc[n][j] + bv;
        if (RELU) v = fmaxf(v, 0.f);
        if (OBF16) ((unsigned short*)outv)[(size_t)row * 128 + col] = f2bf(v);
        else       ((float*)outv)[(size_t)row * 128 + col] = v;
      }
    }
  }
}

// ---- W^T bf16 prep (blocks 0..191) + bcnt zero (block 192, all NBKT entries) ----
__global__ __launch_bounds__(256) void prep_wt(const float* __restrict__ Wp,
                                               const float* __restrict__ Wa,
                                               unsigned short* __restrict__ WpT,
                                               unsigned short* __restrict__ WaT,
                                               int* __restrict__ bcnt) {
  const int b = blockIdx.x;
  if (b == 192) {
    for (int i = threadIdx.x; i < NBKT; i += 256) bcnt[i] = 0;   // covers ALL of bcnt
    return;
  }
  int i = b * 256 + threadIdx.x;
  if (i < 128 * 256) {                 // WpT[128][256] <- Wp[256][128]
    int c = i >> 8, k = i & 255;
    WpT[i] = f2bf(Wp[k * 128 + c]);
  } else if (i < 128 * 256 + 128 * 128) {
    int j = i - 128 * 256;             // WaT[128][128] <- Wa[128][128]
    int c = j >> 7, k = j & 127;
    WaT[j] = f2bf(Wa[k * 128 + c]);
  }
}

// ---- fused independent stages: bin_fill (blocks 0..nchunks-1) + GEMM1 (rest) ----
// 512 threads, 32KB LDS (4 blocks/CU). GEMM1 stages WpT in TWO 32KB K-halves.
// Fill writes fixed-capacity buckets: binned[b*BCAP + rank], rank via bcnt atomics.
__global__ __launch_bounds__(512) void g1_fill(
    const float* __restrict__ features, const unsigned short* __restrict__ WpT,
    const float* __restrict__ bp, unsigned short* __restrict__ xb, int M,
    const int* __restrict__ ei, const float* __restrict__ ew,
    int* __restrict__ bcnt, uint2* __restrict__ binned, int E, int nchunks) {
  __shared__ unsigned short BTl[128 * 128];   // 32KB
  static_assert(2 * NBKT * sizeof(int) <= sizeof(unsigned short) * 128 * 128,
                "fill's cnt+base must fit in BTl alias");
  const int t = threadIdx.x;

  if ((int)blockIdx.x < nchunks) {
    // ---------- bin_fill branch (4096 edges, 8 per thread) ----------
    int* cnt  = (int*)BTl;          // 8KB (NBKT=2048)
    int* base = cnt + NBKT;         // 8KB
    const int c0 = blockIdx.x * 4096;
    for (int i = t; i < NBKT; i += 512) cnt[i] = 0;
    __syncthreads();

    int dst[8]; unsigned pk[8]; int rnk[8];
#pragma unroll
    for (int i = 0; i < 8; ++i) {
      int e = c0 + i * 512 + t;
      if (e < E) {
        int d = ei[E + e];
        dst[i] = d;
        pk[i] = ((unsigned)ei[e] << 16) | (unsigned)f2bf(ew[e]);
        rnk[i] = atomicAdd(&cnt[d >> 5], 1);
      } else dst[i] = -1;
    }
    __syncthreads();
    for (int i = t; i < NBKT; i += 512) {
      int c = cnt[i];
      base[i] = c ? atomicAdd(&bcnt[i], c) : 0;
    }
    __syncthreads();
#pragma unroll
    for (int i = 0; i < 8; ++i) {
      if (dst[i] >= 0) {
        int b = dst[i] >> 5;
        binned[(size_t)b * BCAP + base[b] + rnk[i]] =
            make_uint2((unsigned)(dst[i] & 31), pk[i]);
      }
    }
    return;
  }

  // ---------- GEMM1 branch: xb = bf16(features @ WpT^T + bp), K=256 ----------
  const int bid = blockIdx.x - nchunks;
  const int w = t >> 6;               // wave 0..7
  const int l = t & 63;
  const int r0 = bid * 128 + w * 16;
  const int arow = l & 15;
  const int kq = l >> 4;

  int rowA = r0 + arow; if (rowA >= M) rowA = M - 1;

  f32x4 acc[8];
#pragma unroll
  for (int n = 0; n < 8; ++n) acc[n] = (f32x4){0.f, 0.f, 0.f, 0.f};

#pragma unroll
  for (int h = 0; h < 2; ++h) {       // two 32KB K-halves of WpT
    if (h) __syncthreads();           // all waves done with previous half
#pragma unroll
    for (int c = 0; c < 4; ++c) {     // stage: 2048 chunks of 16B, 4/thread
      int idx = c * 512 + t;
      int row = idx >> 4;             // 0..127
      int within = idx & 15;          // 0..15 (16 chunks per 256B row)
      unsigned swz = (unsigned)(within * 16) ^ ((unsigned)(row & 7) << 4);
      *(uint4*)((char*)BTl + (size_t)row * 256 + swz) =
          *(const uint4*)(WpT + (size_t)row * 256 + h * 128 + within * 8);
    }
    __syncthreads();
#pragma unroll
    for (int ks4 = 0; ks4 < 4; ++ks4) {
      int ks = h * 4 + ks4;
      const float* ap = features + (size_t)rowA * 256 + ks * 32 + kq * 8;
      float4 f0 = *(const float4*)ap;
      float4 f1 = *(const float4*)(ap + 4);
      bf16x8 a;
      a[0] = (short)f2bf(f0.x); a[1] = (short)f2bf(f0.y);
      a[2] = (short)f2bf(f0.z); a[3] = (short)f2bf(f0.w);
      a[4] = (short)f2bf(f1.x); a[5] = (short)f2bf(f1.y);
      a[6] = (short)f2bf(f1.z); a[7] = (short)f2bf(f1.w);
#pragma unroll
      for (int n = 0; n < 8; ++n) {
        int rowB = n * 16 + arow;
        unsigned boff = (unsigned)(ks4 * 64 + kq * 16) ^ ((unsigned)(rowB & 7) << 4);
        bf16x8 b = *(const bf16x8*)((const char*)BTl + (size_t)rowB * 256 + boff);
        acc[n] = __builtin_amdgcn_mfma_f32_16x16x32_bf16(a, b, acc[n], 0, 0, 0);
      }
    }
  }

#pragma unroll
  for (int n = 0; n < 8; ++n) {
    int col = n * 16 + arow;
    float bv = bp[col];
#pragma unroll
    for (int j = 0; j < 4; ++j) {
      int row = r0 + kq * 4 + j;
      if (row < M) {
        float v = acc[n][j] + bv;
        xb[(size_t)row * 128 + col] = f2bf(v);
      }
    }
  }
}

// ---------------- counting-sort + register-accumulate gather ----------------
// One block (512 thr) per 32-dst bucket (1563 blocks -> ~6 blocks/CU).
// Bucket b's entries live at binned[b*BCAP .. b*BCAP+bcnt[b]); single sort pass.
__global__ __launch_bounds__(512) void bucket_sort_gather(
    const unsigned short* __restrict__ xb,
    const uint2* __restrict__ binned,
    const int* __restrict__ bcnt,
    unsigned short* __restrict__ aggb, int N) {
  __shared__ unsigned sorted[CHUNK];   // 4 KB
  __shared__ int cnt[BDST];
  __shared__ int scn[BDST];
  __shared__ int start[BDST];

  const int b = blockIdx.x;
  const int t = threadIdx.x;
  const int w = t >> 6, l = t & 63;
  const int cc0 = l * 2;
  const int n = min(bcnt[b], BCAP);
  const int js = b * BCAP;

  float2 acc[4];
#pragma unroll
  for (int i = 0; i < 4; ++i) acc[i] = make_float2(0.f, 0.f);

  if (t < BDST) cnt[t] = 0;
  __syncthreads();

  int dl[2]; unsigned pk[2]; int rk[2];
#pragma unroll
  for (int q = 0; q < 2; ++q) {
    int i = q * 512 + t;
    if (i < n) {
      uint2 e = binned[js + i];
      dl[q] = (int)e.x; pk[q] = e.y;
      rk[q] = atomicAdd(&cnt[dl[q]], 1);   // native int LDS atomic
    } else dl[q] = -1;
  }
  __syncthreads();

  if (t < BDST) scn[t] = cnt[t];
  __syncthreads();
#pragma unroll
  for (int o = 1; o < BDST; o <<= 1) {
    int v = 0;
    if (t < BDST && t >= o) v = scn[t - o];
    __syncthreads();
    if (t < BDST) scn[t] += v;
    __syncthreads();
  }
  if (t < BDST) start[t] = scn[t] - cnt[t];
  __syncthreads();

#pragma unroll
  for (int q = 0; q < 2; ++q)
    if (dl[q] >= 0) sorted[start[dl[q]] + rk[q]] = pk[q];
  __syncthreads();

  // accumulate: wave w owns dl in [w*4, w*4+4); 8 gathers in flight
  for (int i = 0; i < 4; ++i) {
    const int d = w * 4 + i;
    const int s0 = start[d], c = cnt[d];   // wave-uniform LDS broadcast
    int j = 0;
    for (; j + 8 <= c; j += 8) {
      unsigned p[8], v[8];
#pragma unroll
      for (int q = 0; q < 8; ++q) p[q] = sorted[s0 + j + q];
#pragma unroll
      for (int q = 0; q < 8; ++q)
        v[q] = *(const unsigned*)(xb + (size_t)(p[q] >> 16) * 128 + cc0);
#pragma unroll
      for (int q = 0; q < 8; ++q) {
        float wg = __uint_as_float(p[q] << 16);
        acc[i].x = fmaf(wg, __uint_as_float(v[q] << 16), acc[i].x);
        acc[i].y = fmaf(wg, __uint_as_float(v[q] & 0xFFFF0000u), acc[i].y);
      }
    }
    for (; j + 4 <= c; j += 4) {
      unsigned p[4], v[4];
#pragma unroll
      for (int q = 0; q < 4; ++q) p[q] = sorted[s0 + j + q];
#pragma unroll
      for (int q = 0; q < 4; ++q)
        v[q] = *(const unsigned*)(xb + (size_t)(p[q] >> 16) * 128 + cc0);
#pragma unroll
      for (int q = 0; q < 4; ++q) {
        float wg = __uint_as_float(p[q] << 16);
        acc[i].x = fmaf(wg, __uint_as_float(v[q] << 16), acc[i].x);
        acc[i].y = fmaf(wg, __uint_as_float(v[q] & 0xFFFF0000u), acc[i].y);
      }
    }
    for (; j < c; ++j) {
      unsigned p = sorted[s0 + j];
      unsigned v = *(const unsigned*)(xb + (size_t)(p >> 16) * 128 + cc0);
      float wg = __uint_as_float(p << 16);
      acc[i].x = fmaf(wg, __uint_as_float(v << 16), acc[i].x);
      acc[i].y = fmaf(wg, __uint_as_float(v & 0xFFFF0000u), acc[i].y);
    }
  }

  // writeback: wave w writes its 4 dst rows (coalesced 256B per row)
  const int d0 = b * BDST;
#pragma unroll
  for (int i = 0; i < 4; ++i) {
    int dst = d0 + w * 4 + i;
    if (dst < N) {
      unsigned p = ((unsigned)f2bf(acc[i].y) << 16) | (unsigned)f2bf(acc[i].x);
      *(unsigned*)(aggb + (size_t)dst * 128 + cc0) = p;
    }
  }
}

extern "C" void kernel_launch(void* const* d_in, const int* in_sizes, int n_in,
                              void* d_out, int out_size, void* d_ws, size_t ws_size,
                              hipStream_t stream) {
  const float* features = (const float*)d_in[0];
  const int* ei = (const int*)d_in[1];   // [2, E] int32
  const float* ew = (const float*)d_in[2];
  const float* Wp = (const float*)d_in[3];
  const float* bp = (const float*)d_in[4];
  const float* Wa = (const float*)d_in[5];
  const float* ba = (const float*)d_in[6];

  const int N = in_sizes[0] / 256;  // 50000
  const int E = in_sizes[1] / 2;    // 800000

  float* out = (float*)d_out;

  // Workspace layout (256B-aligned), ~42.5 MB:
  char* ws = (char*)d_ws;
  size_t o = 0;
  unsigned short* xb   = (unsigned short*)(ws + o); o += (size_t)N * 128 * 2;  // 12.8 MB
  o = (o + 255) & ~(size_t)255;
  unsigned short* aggb = (unsigned short*)(ws + o); o += (size_t)N * 128 * 2;  // 12.8 MB
  o = (o + 255) & ~(size_t)255;
  uint2* binned = (uint2*)(ws + o); o += (size_t)NBKT * BCAP * 8;              // 16.8 MB
  o = (o + 255) & ~(size_t)255;
  int* bcnt  = (int*)(ws + o); o += NBKT * 4;
  o = (o + 255) & ~(size_t)255;
  unsigned short* WpT = (unsigned short*)(ws + o); o += (size_t)128 * 256 * 2; // 64 KB
  o = (o + 255) & ~(size_t)255;
  unsigned short* WaT = (unsigned short*)(ws + o); o += (size_t)128 * 128 * 2; // 32 KB

  const int nbkt_real = (N + BDST - 1) / BDST;  // 1563
  const int nchunks = (E + 4095) / 4096;        // 196
  const int g1_blocks = (N + 127) / 128;        // 391

  // 0) W^T prep (blocks 0..191) + bcnt zero (block 192)
  prep_wt<<<193, 256, 0, stream>>>(Wp, Wa, WpT, WaT, bcnt);

  // 1) fused independent stages: bin_fill (blocks 0..195) + GEMM1 (blocks 196..586)
  g1_fill<<<nchunks + g1_blocks, 512, 0, stream>>>(features, WpT, bp, xb, N,
                                                   ei, ew, bcnt, binned, E, nchunks);

  // 2) per-bucket counting-sort + register-accumulated gather (no float atomics)
  bucket_sort_gather<<<nbkt_real, 512, 0, stream>>>(xb, binned, bcnt, aggb, N);

  // 3) out = relu(aggb @ W_agg + b_agg)  (512-thr, 128 rows/block)
  gemm_mfma<128, true, false, false><<<(N + 127) / 128, 512, 0, stream>>>(aggb, WaT, ba, out, N);
}